// Round 1
// baseline (728.136 us; speedup 1.0000x reference)
//
#include <hip/hip_runtime.h>

#define E_EDGES 800000
#define NN 50000
#define D_IN 96
#define D_EDGE 32
#define D_FEAT 128
#define D_OUT 96
#define N_TYPES 4
#define TILE_M 64
#define BPT 1024          // blocks per type in gemm grid
#define LDS_STRIDE 136    // 128 + 8 bf16 pad: keeps 16B alignment, breaks pow2 bank stride

typedef __attribute__((ext_vector_type(8))) __bf16 bf16x8;
typedef __attribute__((ext_vector_type(4))) float floatx4;

// ---------------- pass 1: count edges per type ----------------
__global__ __launch_bounds__(256) void k_count(const int* __restrict__ et,
                                               int* __restrict__ cnt) {
    int tid = threadIdx.x;
    int e = blockIdx.x * 256 + tid;      // E divisible by 256, no tail
    int lane = tid & 63;
    __shared__ int c[N_TYPES];
    if (tid < N_TYPES) c[tid] = 0;
    __syncthreads();
    int ty = et[e];
#pragma unroll
    for (int t = 0; t < N_TYPES; t++) {
        unsigned long long m = __ballot(ty == t);
        if (lane == 0) atomicAdd(&c[t], (int)__popcll(m));
    }
    __syncthreads();
    if (tid < N_TYPES && c[tid] > 0) atomicAdd(&cnt[tid], c[tid]);
}

// ---------------- pass 2: exclusive prefix ----------------
__global__ void k_prefix(const int* __restrict__ cnt, int* __restrict__ base,
                         int* __restrict__ cursor) {
    int b = 0;
    for (int t = 0; t < N_TYPES; t++) { base[t] = b; cursor[t] = b; b += cnt[t]; }
}

// ---------------- pass 3: scatter edge ids into type-sorted perm ----------------
__global__ __launch_bounds__(256) void k_scatter(const int* __restrict__ et,
                                                 int* __restrict__ cursor,
                                                 int* __restrict__ perm) {
    int tid = threadIdx.x;
    int e = blockIdx.x * 256 + tid;
    int lane = tid & 63, w = tid >> 6;
    __shared__ int wcnt[4][N_TYPES];
    __shared__ int woff[4][N_TYPES];
    int ty = et[e];
    unsigned long long mymask = 0;
#pragma unroll
    for (int t = 0; t < N_TYPES; t++) {
        unsigned long long m = __ballot(ty == t);
        if (ty == t) mymask = m;
        if (lane == 0) wcnt[w][t] = (int)__popcll(m);
    }
    __syncthreads();
    if (tid < N_TYPES) {
        int t = tid;
        int tot = wcnt[0][t] + wcnt[1][t] + wcnt[2][t] + wcnt[3][t];
        int gb = atomicAdd(&cursor[t], tot);
#pragma unroll
        for (int ww = 0; ww < 4; ww++) { woff[ww][t] = gb; gb += wcnt[ww][t]; }
    }
    __syncthreads();
    int rank = (int)__popcll(mymask & ((1ULL << lane) - 1ULL));
    perm[woff[w][ty] + rank] = e;
}

// ---------------- pass 4: per-type tiled MFMA gemm + atomic scatter ----------------
// block = 256 threads = 4 waves; each block owns one type, grid-strides over
// 64-edge tiles. W[t] held in registers as bf16 B-fragments (24 frags = 96 VGPR).
__global__ __launch_bounds__(256, 2) void k_gemm(
    const int* __restrict__ perm, const int* __restrict__ cnt,
    const int* __restrict__ base, const int* __restrict__ ei,
    const float* __restrict__ x, const float* __restrict__ ef,
    const float* __restrict__ Wm, const float* __restrict__ bm,
    float* __restrict__ out) {
    int bid = blockIdx.x;
    int t = bid / BPT;
    int b0 = bid - t * BPT;
    int cnt_t = cnt[t];
    int ntiles = (cnt_t + TILE_M - 1) / TILE_M;
    if (b0 >= ntiles) return;
    int base_t = base[t];

    int tid = threadIdx.x;
    int lane = tid & 63, w = tid >> 6;
    int quad = lane >> 4, low = lane & 15;

    __shared__ __bf16 feat[TILE_M * LDS_STRIDE];
    __shared__ int src_lds[TILE_M];
    __shared__ int dst_lds[TILE_M];

    // B fragments: B[k = quad*8+j][n = low] for 6 n-tiles x 4 k-steps
    bf16x8 bfr[24];
#pragma unroll
    for (int nt = 0; nt < 6; nt++) {
#pragma unroll
        for (int ks = 0; ks < 4; ks++) {
            bf16x8 v;
            const float* wp = Wm + ((size_t)t * D_FEAT + ks * 32 + quad * 8) * D_OUT
                              + nt * 16 + low;
#pragma unroll
            for (int j = 0; j < 8; j++) v[j] = (__bf16)wp[j * D_OUT];
            bfr[nt * 4 + ks] = v;
        }
    }
    float bias[6];
#pragma unroll
    for (int nt = 0; nt < 6; nt++) bias[nt] = bm[t * D_OUT + nt * 16 + low];

    for (int tile = b0; tile < ntiles; tile += BPT) {
        int start = base_t + tile * TILE_M;
        int nvalid = min(TILE_M, cnt_t - tile * TILE_M);

        if (tid < TILE_M) {
            int r = tid;
            if (r < nvalid) {
                int e = perm[start + r];
                src_lds[r] = ei[e];
                dst_lds[r] = ei[E_EDGES + e];
            } else {
                src_lds[r] = -1;
                dst_lds[r] = -1;
            }
        }
        __syncthreads();

        // stage feat = [x[src] | abs(ef[src]-ef[dst])] as bf16; zeros for pad rows
#pragma unroll 4
        for (int i = 0; i < (TILE_M * D_FEAT) / 256; i++) {
            int idx = i * 256 + tid;
            int r = idx >> 7;   // /128
            int k = idx & 127;
            float v = 0.0f;
            int s = src_lds[r];
            if (s >= 0) {
                if (k < D_IN) {
                    v = x[(size_t)s * D_IN + k];
                } else {
                    int kk = k - D_IN;
                    v = fabsf(ef[(size_t)s * D_EDGE + kk]
                              - ef[(size_t)dst_lds[r] * D_EDGE + kk]);
                }
            }
            feat[r * LDS_STRIDE + k] = (__bf16)v;
        }
        __syncthreads();

        // A fragments: A[m = low][k = quad*8+j], rows = this wave's 16 edges
        bf16x8 a[4];
        const __bf16* ap = feat + (w * 16 + low) * LDS_STRIDE + quad * 8;
#pragma unroll
        for (int ks = 0; ks < 4; ks++) a[ks] = *(const bf16x8*)(ap + ks * 32);

#pragma unroll
        for (int nt = 0; nt < 6; nt++) {
            floatx4 acc = {0.f, 0.f, 0.f, 0.f};
#pragma unroll
            for (int ks = 0; ks < 4; ks++)
                acc = __builtin_amdgcn_mfma_f32_16x16x32_bf16(a[ks], bfr[nt * 4 + ks],
                                                              acc, 0, 0, 0);
            int col = nt * 16 + low;
#pragma unroll
            for (int rg = 0; rg < 4; rg++) {
                int r = w * 16 + quad * 4 + rg;   // C/D: row = quad*4 + reg
                if (r < nvalid)
                    atomicAdd(&out[(size_t)dst_lds[r] * D_OUT + col],
                              0.25f * (acc[rg] + bias[nt]));
            }
        }
        __syncthreads();
    }
}

extern "C" void kernel_launch(void* const* d_in, const int* in_sizes, int n_in,
                              void* d_out, int out_size, void* d_ws, size_t ws_size,
                              hipStream_t stream) {
    const float* x  = (const float*)d_in[0];
    const float* ef = (const float*)d_in[1];
    const int*   ei = (const int*)d_in[2];
    const int*   et = (const int*)d_in[3];
    const float* Wm = (const float*)d_in[4];
    const float* bm = (const float*)d_in[5];
    float* out = (float*)d_out;

    int* cnt    = (int*)d_ws;   // [4]
    int* base   = cnt + 4;      // [4]
    int* cursor = cnt + 8;      // [4]
    int* perm   = cnt + 16;     // [E]  (~3.2 MB of ws)

    hipMemsetAsync(cnt, 0, N_TYPES * sizeof(int), stream);
    hipMemsetAsync(d_out, 0, (size_t)out_size * sizeof(float), stream);

    k_count  <<<E_EDGES / 256, 256, 0, stream>>>(et, cnt);
    k_prefix <<<1, 1, 0, stream>>>(cnt, base, cursor);
    k_scatter<<<E_EDGES / 256, 256, 0, stream>>>(et, cursor, perm);
    k_gemm   <<<N_TYPES * BPT, 256, 0, stream>>>(perm, cnt, base, ei, x, ef, Wm, bm, out);
}

// Round 4
// 418.025 us; speedup vs baseline: 1.7418x; 1.7418x over previous
//
#include <hip/hip_runtime.h>

#define E_EDGES 800000
#define NN 50000
#define NND 50048            // padded node count (multiple of 32)
#define NPB 32               // nodes per block in fused kernel
#define NSCAN 50176          // SCAN_BLOCKS*256 scan domain (>= NND+1)
#define SCAN_BLOCKS 196
#define D_IN 96
#define D_EDGE 32
#define D_OUT 96
#define KSUM 512             // 4 types x 128 feat dims
#define SSTRIDE 520          // +8 bf16 pad (row stride 1040 B, 16B-aligned, 2-way bank alias = free)

typedef __attribute__((ext_vector_type(8))) __bf16 bf16x8;
typedef __attribute__((ext_vector_type(4))) float floatx4;

// ---------- pass 1: histogram of dst ----------
__global__ __launch_bounds__(256) void k_hist(const int* __restrict__ ei,
                                              int* __restrict__ deg) {
    int e = blockIdx.x * 256 + threadIdx.x;     // E divisible by 256
    atomicAdd(&deg[ei[E_EDGES + e]], 1);
}

// ---------- pass 2: two-level exclusive scan over NSCAN ----------
__global__ __launch_bounds__(256) void k_scan_a(const int* __restrict__ deg,
                                                int* __restrict__ off,
                                                int* __restrict__ bsum) {
    __shared__ int tmp[256];
    int tid = threadIdx.x, gid = blockIdx.x * 256 + tid;
    int v = deg[gid];
    tmp[tid] = v; __syncthreads();
    for (int d = 1; d < 256; d <<= 1) {
        int t = (tid >= d) ? tmp[tid - d] : 0;
        __syncthreads();
        tmp[tid] += t;
        __syncthreads();
    }
    off[gid] = tmp[tid] - v;                    // exclusive
    if (tid == 255) bsum[blockIdx.x] = tmp[255];
}

__global__ __launch_bounds__(256) void k_scan_b(int* __restrict__ bsum) {
    __shared__ int tmp[256];
    int tid = threadIdx.x;
    int v = (tid < SCAN_BLOCKS) ? bsum[tid] : 0;
    tmp[tid] = v; __syncthreads();
    for (int d = 1; d < 256; d <<= 1) {
        int t = (tid >= d) ? tmp[tid - d] : 0;
        __syncthreads();
        tmp[tid] += t;
        __syncthreads();
    }
    if (tid < SCAN_BLOCKS) bsum[tid] = tmp[tid] - v;   // exclusive block bases
}

__global__ __launch_bounds__(256) void k_scan_c(int* __restrict__ off,
                                                const int* __restrict__ bsum,
                                                int* __restrict__ cursor) {
    int gid = blockIdx.x * 256 + threadIdx.x;
    int v = off[gid] + bsum[blockIdx.x];
    off[gid] = v;
    cursor[gid] = v;
}

// ---------- pass 3: scatter packed (src | type<<20) into dst-sorted perm ----------
__global__ __launch_bounds__(256) void k_scat(const int* __restrict__ ei,
                                              const int* __restrict__ et,
                                              int* __restrict__ cursor,
                                              int* __restrict__ perm) {
    int e = blockIdx.x * 256 + threadIdx.x;
    int src = ei[e];
    int ty  = et[e];
    int pos = atomicAdd(&cursor[ei[E_EDGES + e]], 1);
    perm[pos] = src | (ty << 20);
}

// ---------- pass 4: WT bf16 [96][512]: WT[n][k] = W[k/128][k%128][n] = Wm[k*96+n] ----------
__global__ __launch_bounds__(512) void k_wprep(const float* __restrict__ Wm,
                                               __bf16* __restrict__ WT) {
    int n = blockIdx.x, k = threadIdx.x;        // 96 blocks x 512 threads
    WT[n * KSUM + k] = (__bf16)Wm[(size_t)k * 96 + n];
}

// ---------- pass 5 (fused): per-node type-sums in LDS -> MFMA GEMM -> store ----------
// block = 256 threads = 4 waves, owns 32 nodes. Phase A: wave w serially sums
// edges of nodes w*8..w*8+7 (lane holds feat dims {lane, lane+64}), rows to LDS
// as bf16. Phase B: 32x96 GEMM vs WT (K=512), bias = sum_t cnt[t]*b[t] in fp32.
__global__ __launch_bounds__(256) void k_fused(
    const int* __restrict__ off, const int* __restrict__ perm,
    const float* __restrict__ x, const float* __restrict__ ef,
    const __bf16* __restrict__ WT, const float* __restrict__ bm,
    float* __restrict__ out) {
    __shared__ __align__(16) __bf16 Sl[NPB][SSTRIDE];
    __shared__ int pk[4][64];
    __shared__ float cnts[NPB][4];
    __shared__ float bl[4 * 96];

    int tid = threadIdx.x, lane = tid & 63, w = tid >> 6;
    // BUGFIX R3->R4: bl has 384 entries but block is 256 threads; the old
    // `if (tid < 384)` left bl[256..383] (type-2 cols 64..95 and all of
    // type-3 bias) as uninitialized LDS -> absmax 8.3. Strided fill:
    for (int i = tid; i < 4 * 96; i += 256) bl[i] = bm[i];

    // ---- phase A ----
    for (int j = 0; j < 8; j++) {
        int lr = w * 8 + j;
        int n = blockIdx.x * NPB + lr;
        int beg = off[n], end = off[n + 1];
        float s0a = 0, s0b = 0, s1a = 0, s1b = 0, s2a = 0, s2b = 0, s3a = 0, s3b = 0;
        int c0 = 0, c1 = 0, c2 = 0, c3 = 0;
        float efd = 0.f;
        if (beg < end && lane >= 32) efd = ef[(size_t)n * D_EDGE + lane - 32];

        for (int cb = beg; cb < end; cb += 64) {
            int nval = min(64, end - cb);
            if (lane < nval) pk[w][lane] = perm[cb + lane];
            for (int i = 0; i < nval; i++) {
                int v = pk[w][i];                // wave-uniform broadcast read
                int src = v & 0xFFFFF;
                int ty = v >> 20;
                const float* xp = x + (size_t)src * D_IN;
                float v1 = xp[lane];
                float v2 = (lane < 32)
                               ? xp[64 + lane]
                               : fabsf(ef[(size_t)src * D_EDGE + lane - 32] - efd);
                if      (ty == 0) { s0a += v1; s0b += v2; c0++; }
                else if (ty == 1) { s1a += v1; s1b += v2; c1++; }
                else if (ty == 2) { s2a += v1; s2b += v2; c2++; }
                else              { s3a += v1; s3b += v2; c3++; }
            }
        }
        __bf16* sp = &Sl[lr][0];
        sp[0 * 128 + lane] = (__bf16)s0a;  sp[0 * 128 + 64 + lane] = (__bf16)s0b;
        sp[1 * 128 + lane] = (__bf16)s1a;  sp[1 * 128 + 64 + lane] = (__bf16)s1b;
        sp[2 * 128 + lane] = (__bf16)s2a;  sp[2 * 128 + 64 + lane] = (__bf16)s2b;
        sp[3 * 128 + lane] = (__bf16)s3a;  sp[3 * 128 + 64 + lane] = (__bf16)s3b;
        if (lane == 0) {
            cnts[lr][0] = (float)c0; cnts[lr][1] = (float)c1;
            cnts[lr][2] = (float)c2; cnts[lr][3] = (float)c3;
        }
    }
    __syncthreads();

    // ---- phase B ----
    int quad = lane >> 4, low = lane & 15;
    int rt = w & 1;                      // row tile (16 rows)
    int cbase = (w >> 1) * 3;            // 3 col tiles per wave

    bf16x8 a[16];                        // A frags: m=low, k=ks*32+quad*8+j
    const __bf16* ap = &Sl[rt * 16 + low][0] + quad * 8;
#pragma unroll
    for (int ks = 0; ks < 16; ks++) a[ks] = *(const bf16x8*)(ap + ks * 32);

#pragma unroll
    for (int c3 = 0; c3 < 3; c3++) {
        int ct = cbase + c3;
        floatx4 acc = {0.f, 0.f, 0.f, 0.f};
        const __bf16* bp = WT + (size_t)(ct * 16 + low) * KSUM + quad * 8;
#pragma unroll
        for (int ks = 0; ks < 16; ks++)
            acc = __builtin_amdgcn_mfma_f32_16x16x32_bf16(a[ks],
                      *(const bf16x8*)(bp + ks * 32), acc, 0, 0, 0);
        int col = ct * 16 + low;
#pragma unroll
        for (int rg = 0; rg < 4; rg++) {
            int r = rt * 16 + quad * 4 + rg;          // C/D: row = quad*4+reg
            int g = blockIdx.x * NPB + r;
            if (g < NN) {
                float bias = cnts[r][0] * bl[col]       + cnts[r][1] * bl[96 + col]
                           + cnts[r][2] * bl[192 + col] + cnts[r][3] * bl[288 + col];
                out[(size_t)g * D_OUT + col] = 0.25f * (acc[rg] + bias);
            }
        }
    }
}

extern "C" void kernel_launch(void* const* d_in, const int* in_sizes, int n_in,
                              void* d_out, int out_size, void* d_ws, size_t ws_size,
                              hipStream_t stream) {
    const float* x  = (const float*)d_in[0];
    const float* ef = (const float*)d_in[1];
    const int*   ei = (const int*)d_in[2];
    const int*   et = (const int*)d_in[3];
    const float* Wm = (const float*)d_in[4];
    const float* bm = (const float*)d_in[5];
    float* out = (float*)d_out;

    int* deg    = (int*)d_ws;            // NSCAN
    int* off    = deg + NSCAN;           // NSCAN
    int* bsum   = off + NSCAN;           // 256
    int* cursor = bsum + 256;            // NSCAN
    int* perm   = cursor + NSCAN;        // E_EDGES (packed src|type)
    __bf16* WT  = (__bf16*)(perm + E_EDGES);   // 96*512 bf16, 16B-aligned offset
    // total ws: ~3.9 MB

    hipMemsetAsync(deg, 0, NSCAN * sizeof(int), stream);

    k_hist  <<<E_EDGES / 256, 256, 0, stream>>>(ei, deg);
    k_scan_a<<<SCAN_BLOCKS, 256, 0, stream>>>(deg, off, bsum);
    k_scan_b<<<1, 256, 0, stream>>>(bsum);
    k_scan_c<<<SCAN_BLOCKS, 256, 0, stream>>>(off, bsum, cursor);
    k_scat  <<<E_EDGES / 256, 256, 0, stream>>>(ei, et, cursor, perm);
    k_wprep <<<96, 512, 0, stream>>>(Wm, WT);
    k_fused <<<NND / NPB, 256, 0, stream>>>(off, perm, x, ef, WT, bm, out);
}